// Round 1
// baseline (945.742 us; speedup 1.0000x reference)
//
#include <hip/hip_runtime.h>

// 2-layer GCN, N=100000 nodes (F0=5, F1=16, F2=1), E=3200000 edges.
// out[i] = dinv[i]*(sum_in z + z[i]) + b2,  z = dinv * (relu(dinv*(sum_in g + g)+b1) @ W2),
// g = dinv * (x@W1),  dinv[i] = rsqrt(1 + indegree(i)).

constexpr int F = 16;

__global__ void k_node_prep(const float* __restrict__ x,
                            const float* __restrict__ W1,
                            float* __restrict__ h,
                            int* __restrict__ deg,
                            float* __restrict__ agg,
                            float* __restrict__ outacc,
                            int n) {
  __shared__ float sW1[5 * F];
  int t = threadIdx.x;
  if (t < 5 * F) sW1[t] = W1[t];
  __syncthreads();
  int i = blockIdx.x * blockDim.x + t;
  if (i >= n) return;
  float xv[5];
#pragma unroll
  for (int k = 0; k < 5; ++k) xv[k] = x[i * 5 + k];
#pragma unroll
  for (int q = 0; q < 4; ++q) {
    float4 v;
    float* vp = (float*)&v;
#pragma unroll
    for (int j = 0; j < 4; ++j) {
      int f = q * 4 + j;
      float acc = 0.f;
#pragma unroll
      for (int k = 0; k < 5; ++k) acc = fmaf(xv[k], sW1[k * F + f], acc);
      vp[j] = acc;
    }
    ((float4*)h)[(size_t)i * 4 + q] = v;
    ((float4*)agg)[(size_t)i * 4 + q] = make_float4(0.f, 0.f, 0.f, 0.f);
  }
  deg[i] = 0;
  outacc[i] = 0.f;
}

__global__ void k_deg(const int* __restrict__ dst, int* __restrict__ deg, int e) {
  int t = blockIdx.x * blockDim.x + threadIdx.x;
  if (t < e) atomicAdd(&deg[dst[t]], 1);
}

__global__ void k_scale(float* __restrict__ h, const int* __restrict__ deg,
                        float* __restrict__ dinv, int n) {
  int i = blockIdx.x * blockDim.x + threadIdx.x;
  if (i >= n) return;
  float d = rsqrtf((float)(deg[i] + 1));  // +1 self-loop
  dinv[i] = d;
#pragma unroll
  for (int q = 0; q < 4; ++q) {
    float4 v = ((float4*)h)[(size_t)i * 4 + q];
    v.x *= d; v.y *= d; v.z *= d; v.w *= d;
    ((float4*)h)[(size_t)i * 4 + q] = v;
  }
}

// 4 threads per edge; each gathers one float4 of g[src] and scatters 4 atomics.
__global__ void k_scatter1(const int* __restrict__ src, const int* __restrict__ dst,
                           const float* __restrict__ g, float* __restrict__ agg, int e) {
  int t = blockIdx.x * blockDim.x + threadIdx.x;
  int ei = t >> 2, q = t & 3;
  if (ei >= e) return;
  int s = src[ei];
  int d = dst[ei];
  float4 v = ((const float4*)g)[(size_t)s * 4 + q];
  float* base = agg + (size_t)d * F + q * 4;
  atomicAdd(base + 0, v.x);
  atomicAdd(base + 1, v.y);
  atomicAdd(base + 2, v.z);
  atomicAdd(base + 3, v.w);
}

__global__ void k_finish1(const float* __restrict__ agg, const float* __restrict__ g,
                          const float* __restrict__ dinv, const float* __restrict__ b1,
                          const float* __restrict__ W2, float* __restrict__ z, int n) {
  __shared__ float sW2[F], sb1[F];
  int t = threadIdx.x;
  if (t < F) { sW2[t] = W2[t]; sb1[t] = b1[t]; }
  __syncthreads();
  int i = blockIdx.x * blockDim.x + t;
  if (i >= n) return;
  float d = dinv[i];
  float acc = 0.f;
#pragma unroll
  for (int q = 0; q < 4; ++q) {
    float4 a = ((const float4*)agg)[(size_t)i * 4 + q];
    float4 gv = ((const float4*)g)[(size_t)i * 4 + q];
    float vs[4] = {a.x + gv.x, a.y + gv.y, a.z + gv.z, a.w + gv.w};
#pragma unroll
    for (int j = 0; j < 4; ++j) {
      float v = fmaf(d, vs[j], sb1[q * 4 + j]);
      v = fmaxf(v, 0.f);
      acc = fmaf(v, sW2[q * 4 + j], acc);
    }
  }
  z[i] = d * acc;  // pre-scaled by dinv for the layer-2 message
}

__global__ void k_scatter2(const int* __restrict__ src, const int* __restrict__ dst,
                           const float* __restrict__ z, float* __restrict__ outacc, int e) {
  int t = blockIdx.x * blockDim.x + threadIdx.x;
  if (t < e) atomicAdd(&outacc[dst[t]], z[src[t]]);
}

__global__ void k_finish2(const float* __restrict__ outacc, const float* __restrict__ z,
                          const float* __restrict__ dinv, const float* __restrict__ b2,
                          float* __restrict__ out, int n) {
  int i = blockIdx.x * blockDim.x + threadIdx.x;
  if (i < n) out[i] = fmaf(dinv[i], outacc[i] + z[i], b2[0]);
}

extern "C" void kernel_launch(void* const* d_in, const int* in_sizes, int n_in,
                              void* d_out, int out_size, void* d_ws, size_t ws_size,
                              hipStream_t stream) {
  const float* x  = (const float*)d_in[0];
  const float* W1 = (const float*)d_in[1];
  const float* b1 = (const float*)d_in[2];
  const float* W2 = (const float*)d_in[3];
  const float* b2 = (const float*)d_in[4];
  const int*   ei = (const int*)d_in[5];

  int n = in_sizes[0] / 5;
  int e = in_sizes[5] / 2;
  const int* src = ei;
  const int* dst = ei + e;

  char* ws = (char*)d_ws;
  float* h      = (float*)ws; ws += (size_t)n * F * sizeof(float);   // h, then g (in place)
  float* agg    = (float*)ws; ws += (size_t)n * F * sizeof(float);
  float* dinv   = (float*)ws; ws += (size_t)n * sizeof(float);
  float* z      = (float*)ws; ws += (size_t)n * sizeof(float);
  float* outacc = (float*)ws; ws += (size_t)n * sizeof(float);
  int*   deg    = (int*)ws;   ws += (size_t)n * sizeof(int);

  float* out = (float*)d_out;

  int bn  = (n + 255) / 256;
  int be  = (e + 255) / 256;
  long long te4 = (long long)e * 4;
  int be4 = (int)((te4 + 255) / 256);

  k_node_prep<<<bn, 256, 0, stream>>>(x, W1, h, deg, agg, outacc, n);
  k_deg<<<be, 256, 0, stream>>>(dst, deg, e);
  k_scale<<<bn, 256, 0, stream>>>(h, deg, dinv, n);
  k_scatter1<<<be4, 256, 0, stream>>>(src, dst, h, agg, e);
  k_finish1<<<bn, 256, 0, stream>>>(agg, h, dinv, b1, W2, z, n);
  k_scatter2<<<be, 256, 0, stream>>>(src, dst, z, outacc, e);
  k_finish2<<<bn, 256, 0, stream>>>(outacc, z, dinv, b2, out, n);
}

// Round 2
// 580.911 us; speedup vs baseline: 1.6280x; 1.6280x over previous
//
#include <hip/hip_runtime.h>

// 2-layer GCN, N=100000 nodes (F0=5, F1=16, F2=1), E=3200000 edges.
// CSR-gather formulation: no float atomics.
//   dinv[i] = rsqrt(1 + indeg(i))
//   g = dinv * (x@W1)
//   z[i] = dinv[i] * (relu(dinv[i]*(sum_{s->i} g[s] + g[i]) + b1) @ W2)
//   out[i] = dinv[i]*(sum_{s->i} z[s] + z[i]) + b2

constexpr int F = 16;

__global__ void k_node_prep(const float* __restrict__ x,
                            const float* __restrict__ W1,
                            float* __restrict__ h,
                            int* __restrict__ deg,
                            int* __restrict__ cursor,
                            int n) {
  __shared__ float sW1[5 * F];
  int t = threadIdx.x;
  if (t < 5 * F) sW1[t] = W1[t];
  __syncthreads();
  int i = blockIdx.x * blockDim.x + t;
  if (i >= n) return;
  float xv[5];
#pragma unroll
  for (int k = 0; k < 5; ++k) xv[k] = x[i * 5 + k];
#pragma unroll
  for (int q = 0; q < 4; ++q) {
    float4 v;
    float* vp = (float*)&v;
#pragma unroll
    for (int j = 0; j < 4; ++j) {
      int f = q * 4 + j;
      float acc = 0.f;
#pragma unroll
      for (int k = 0; k < 5; ++k) acc = fmaf(xv[k], sW1[k * F + f], acc);
      vp[j] = acc;
    }
    ((float4*)h)[(size_t)i * 4 + q] = v;
  }
  deg[i] = 0;
  cursor[i] = 0;
}

__global__ void k_deg(const int* __restrict__ dst, int* __restrict__ deg, int e) {
  int t = blockIdx.x * blockDim.x + threadIdx.x;
  if (t < e) atomicAdd(&deg[dst[t]], 1);
}

// Single-block exclusive scan: deg[0..n) -> off[0..n], off[n]=e.
__global__ void __launch_bounds__(1024) k_scan(const int* __restrict__ deg,
                                               int* __restrict__ off, int n, int e) {
  const int T = 1024;
  __shared__ int s[T];
  int t = threadIdx.x;
  int chunk = (n + T - 1) / T;
  int lo = t * chunk;
  int hi = lo + chunk; if (hi > n) hi = n;
  int sum = 0;
  for (int i = lo; i < hi; ++i) sum += deg[i];
  s[t] = sum;
  __syncthreads();
  for (int d = 1; d < T; d <<= 1) {
    int v = (t >= d) ? s[t - d] : 0;
    __syncthreads();
    s[t] += v;
    __syncthreads();
  }
  int run = s[t] - sum;  // exclusive prefix of this thread's chunk
  for (int i = lo; i < hi; ++i) { off[i] = run; run += deg[i]; }
  if (t == 0) off[n] = e;
}

__global__ void k_fill(const int* __restrict__ src, const int* __restrict__ dst,
                       const int* __restrict__ off, int* __restrict__ cursor,
                       int* __restrict__ adj, int e) {
  int t = blockIdx.x * blockDim.x + threadIdx.x;
  if (t >= e) return;
  int d = dst[t];
  int pos = atomicAdd(&cursor[d], 1);
  adj[off[d] + pos] = src[t];
}

__global__ void k_scale(float* __restrict__ h, const int* __restrict__ deg,
                        float* __restrict__ dinv, int n) {
  int i = blockIdx.x * blockDim.x + threadIdx.x;
  if (i >= n) return;
  float d = rsqrtf((float)(deg[i] + 1));  // +1 self-loop
  dinv[i] = d;
#pragma unroll
  for (int q = 0; q < 4; ++q) {
    float4 v = ((float4*)h)[(size_t)i * 4 + q];
    v.x *= d; v.y *= d; v.z *= d; v.w *= d;
    ((float4*)h)[(size_t)i * 4 + q] = v;
  }
}

// 16 lanes per node: gather-aggregate g over in-neighbors, fused ReLU + @W2 -> z.
__global__ void k_agg1(const float* __restrict__ g, const int* __restrict__ off,
                       const int* __restrict__ adj, const float* __restrict__ dinv,
                       const float* __restrict__ b1, const float* __restrict__ W2,
                       float* __restrict__ z, int n) {
  __shared__ float sW2[F], sb1[F];
  int t = threadIdx.x;
  if (t < F) { sW2[t] = W2[t]; sb1[t] = b1[t]; }
  __syncthreads();
  int lane = t & 15, local = t >> 4;
  int i = blockIdx.x * 16 + local;
  if (i >= n) return;
  float di = dinv[i];
  float acc = g[(size_t)i * F + lane];  // self-loop message
  int k = off[i], k1 = off[i + 1];
  for (; k + 1 < k1; k += 2) {
    int s0 = adj[k], s1 = adj[k + 1];
    float v0 = g[(size_t)s0 * F + lane];
    float v1 = g[(size_t)s1 * F + lane];
    acc += v0 + v1;
  }
  if (k < k1) acc += g[(size_t)adj[k] * F + lane];
  float v = fmaxf(fmaf(di, acc, sb1[lane]), 0.f);
  float c = v * sW2[lane];
  c += __shfl_xor(c, 1, 16);
  c += __shfl_xor(c, 2, 16);
  c += __shfl_xor(c, 4, 16);
  c += __shfl_xor(c, 8, 16);
  if (lane == 0) z[i] = di * c;
}

// 8 lanes per node: gather-aggregate z, fused bias -> out.
__global__ void k_agg2(const float* __restrict__ z, const int* __restrict__ off,
                       const int* __restrict__ adj, const float* __restrict__ dinv,
                       const float* __restrict__ b2, float* __restrict__ out, int n) {
  int t = threadIdx.x;
  int lane = t & 7, local = t >> 3;
  int i = blockIdx.x * 32 + local;
  if (i >= n) return;
  float acc = (lane == 0) ? z[i] : 0.f;  // self-loop
  int k1 = off[i + 1];
  for (int k = off[i] + lane; k < k1; k += 8) acc += z[adj[k]];
  acc += __shfl_xor(acc, 1, 8);
  acc += __shfl_xor(acc, 2, 8);
  acc += __shfl_xor(acc, 4, 8);
  if (lane == 0) out[i] = fmaf(dinv[i], acc, b2[0]);
}

extern "C" void kernel_launch(void* const* d_in, const int* in_sizes, int n_in,
                              void* d_out, int out_size, void* d_ws, size_t ws_size,
                              hipStream_t stream) {
  const float* x  = (const float*)d_in[0];
  const float* W1 = (const float*)d_in[1];
  const float* b1 = (const float*)d_in[2];
  const float* W2 = (const float*)d_in[3];
  const float* b2 = (const float*)d_in[4];
  const int*   ei = (const int*)d_in[5];

  int n = in_sizes[0] / 5;
  int e = in_sizes[5] / 2;
  const int* src = ei;
  const int* dst = ei + e;

  char* ws = (char*)d_ws;
  float* h      = (float*)ws; ws += (size_t)n * F * sizeof(float);   // h -> g in place
  int*   adj    = (int*)ws;   ws += (size_t)e * sizeof(int);
  int*   off    = (int*)ws;   ws += (size_t)(n + 1) * sizeof(int);
  int*   deg    = (int*)ws;   ws += (size_t)n * sizeof(int);
  int*   cursor = (int*)ws;   ws += (size_t)n * sizeof(int);
  float* dinv   = (float*)ws; ws += (size_t)n * sizeof(float);
  float* z      = (float*)ws; ws += (size_t)n * sizeof(float);

  float* out = (float*)d_out;

  int bn  = (n + 255) / 256;
  int be  = (e + 255) / 256;

  k_node_prep<<<bn, 256, 0, stream>>>(x, W1, h, deg, cursor, n);
  k_deg<<<be, 256, 0, stream>>>(dst, deg, e);
  k_scan<<<1, 1024, 0, stream>>>(deg, off, n, e);
  k_scale<<<bn, 256, 0, stream>>>(h, deg, dinv, n);
  k_fill<<<be, 256, 0, stream>>>(src, dst, off, cursor, adj, e);
  k_agg1<<<(n + 15) / 16, 256, 0, stream>>>(h, off, adj, dinv, b1, W2, z, n);
  k_agg2<<<(n + 31) / 32, 256, 0, stream>>>(z, off, adj, dinv, b2, out, n);
}

// Round 3
// 223.878 us; speedup vs baseline: 4.2244x; 2.5948x over previous
//
#include <hip/hip_runtime.h>

// 2-layer GCN, N=100000 (F0=5, F1=16, F2=1), E=3200000.
// Binned formulation (no global float atomics, no scattered 4B writes):
//   bin b owns nodes [b*256, b*256+256); entry = (dst&255)<<24 | src.
//   y[i]    = dinv[i] * x[i]                  (5 floats, padded to 8; 3.2MB L2-resident)
//   A5[i]   = sum_{s->i} y[s] + y[i]          (LDS accumulate per bin)
//   z[i]    = dinv[i] * (relu(dinv[i]*(A5[i]@W1) + b1) @ W2)
//   out[i]  = dinv[i] * (sum_{s->i} z[s] + z[i]) + b2

constexpr int CHUNK = 4096;   // edges per k_place block
constexpr int RANGE = 256;    // nodes per bin

// ---- pass 1: per-bin edge counts -------------------------------------------
__global__ void k_count(const int* __restrict__ dst, int* __restrict__ binTotal,
                        int e, int nb) {
  extern __shared__ int sh[];
  int* hist = sh;  // nb ints
  for (int b = threadIdx.x; b < nb; b += blockDim.x) hist[b] = 0;
  __syncthreads();
  int stride = gridDim.x * blockDim.x;
  for (int i = blockIdx.x * blockDim.x + threadIdx.x; i < e; i += stride)
    atomicAdd(&hist[dst[i] >> 8], 1);
  __syncthreads();
  for (int b = threadIdx.x; b < nb; b += blockDim.x)
    if (hist[b]) atomicAdd(&binTotal[b], hist[b]);
}

// ---- pass 2: scan bin totals -> binOff, init cursor ------------------------
__global__ void __launch_bounds__(512) k_scan(const int* __restrict__ binTotal,
                                              int* __restrict__ binOff,
                                              int* __restrict__ cursor,
                                              int nb, int e) {
  __shared__ int s[512];
  int t = threadIdx.x;
  int v = (t < nb) ? binTotal[t] : 0;
  s[t] = v;
  __syncthreads();
  for (int d = 1; d < 512; d <<= 1) {
    int u = (t >= d) ? s[t - d] : 0;
    __syncthreads();
    s[t] += u;
    __syncthreads();
  }
  if (t < nb) {
    int excl = s[t] - v;
    binOff[t] = excl;
    cursor[t] = excl;
  }
  if (t == 0) binOff[nb] = e;
}

// ---- pass 3: LDS counting-sort each chunk into bins (coalesced writes) -----
__global__ void __launch_bounds__(256) k_place(const int* __restrict__ src,
                                               const int* __restrict__ dst,
                                               int* __restrict__ cursor,
                                               int* __restrict__ bins,
                                               int e, int nb) {
  __shared__ int entry4[CHUNK];
  __shared__ short bin2[CHUNK];
  __shared__ int hist[512], scan[512], lofs[512], base[512], pcur[512];
  int t = threadIdx.x;
  int e0 = blockIdx.x * CHUNK;
  int cnt = e - e0; if (cnt > CHUNK) cnt = CHUNK;

  for (int b = t; b < 512; b += 256) { hist[b] = 0; }
  __syncthreads();
  for (int i = t; i < cnt; i += 256) atomicAdd(&hist[dst[e0 + i] >> 8], 1);
  __syncthreads();
  // inclusive scan of hist[0..511] with 256 threads (2 elems each)
  scan[t] = hist[t]; scan[t + 256] = hist[t + 256];
  __syncthreads();
  for (int d = 1; d < 512; d <<= 1) {
    int v0 = (t >= d) ? scan[t - d] : 0;
    int v1 = (t + 256 >= d) ? scan[t + 256 - d] : 0;
    __syncthreads();
    scan[t] += v0; scan[t + 256] += v1;
    __syncthreads();
  }
  for (int b = t; b < 512; b += 256) {
    int lo = scan[b] - hist[b];
    lofs[b] = lo;
    pcur[b] = lo;
    if (b < nb && hist[b]) base[b] = atomicAdd(&cursor[b], hist[b]);
  }
  __syncthreads();
  // bin-sort chunk into LDS
  for (int i = t; i < cnt; i += 256) {
    int d = dst[e0 + i];
    int b = d >> 8;
    int slot = atomicAdd(&pcur[b], 1);
    entry4[slot] = ((d & 255) << 24) | src[e0 + i];
    bin2[slot] = (short)b;
  }
  __syncthreads();
  // linear write-out: consecutive slots in a bin-run -> consecutive global pos
  for (int i = t; i < cnt; i += 256) {
    int b = bin2[i];
    bins[base[b] + (i - lofs[b])] = entry4[i];
  }
}

// ---- pass 4: per-bin degree count; write dinv and y = dinv*x (padded 8) ----
__global__ void __launch_bounds__(256) k_deg_y(const int* __restrict__ bins,
                                               const int* __restrict__ binOff,
                                               const float* __restrict__ x,
                                               float* __restrict__ dinv,
                                               float* __restrict__ y, int n) {
  __shared__ int deg[RANGE];
  int t = threadIdx.x;
  deg[t] = 0;
  __syncthreads();
  int b = blockIdx.x;
  int k0 = binOff[b], k1 = binOff[b + 1];
  for (int k = k0 + t; k < k1; k += 256) atomicAdd(&deg[((unsigned)bins[k]) >> 24], 1);
  __syncthreads();
  int node = b * RANGE + t;
  if (node >= n) return;
  float d = rsqrtf((float)(deg[t] + 1));
  dinv[node] = d;
  float4 a, c;
  a.x = d * x[node * 5 + 0];
  a.y = d * x[node * 5 + 1];
  a.z = d * x[node * 5 + 2];
  a.w = d * x[node * 5 + 3];
  c.x = d * x[node * 5 + 4];
  c.y = c.z = c.w = 0.f;
  ((float4*)y)[(size_t)node * 2 + 0] = a;
  ((float4*)y)[(size_t)node * 2 + 1] = c;
}

// ---- pass 5: layer-1 aggregate in 5-dim, fused @W1 + relu + @W2 -> z -------
__global__ void __launch_bounds__(256) k_agg1(const int* __restrict__ bins,
                                              const int* __restrict__ binOff,
                                              const float* __restrict__ y,
                                              const float* __restrict__ dinv,
                                              const float* __restrict__ W1,
                                              const float* __restrict__ b1,
                                              const float* __restrict__ W2,
                                              float* __restrict__ z, int n) {
  __shared__ float acc[RANGE * 5];
  __shared__ float sW1[80], sb1[16], sW2[16];
  int t = threadIdx.x;
  if (t < 80) sW1[t] = W1[t];
  if (t >= 80 && t < 96) sb1[t - 80] = b1[t - 80];
  if (t >= 96 && t < 112) sW2[t - 96] = W2[t - 96];
#pragma unroll
  for (int j = 0; j < 5; ++j) acc[t + j * RANGE] = 0.f;  // [j][node] layout
  __syncthreads();
  int b = blockIdx.x;
  int k0 = binOff[b], k1 = binOff[b + 1];
  for (int k = k0 + t; k < k1; k += 256) {
    unsigned e4 = (unsigned)bins[k];
    int dl = e4 >> 24;
    int s = e4 & 0xFFFFFF;
    float4 v0 = ((const float4*)y)[(size_t)s * 2];
    float v4 = y[(size_t)s * 8 + 4];
    atomicAdd(&acc[dl + 0 * RANGE], v0.x);
    atomicAdd(&acc[dl + 1 * RANGE], v0.y);
    atomicAdd(&acc[dl + 2 * RANGE], v0.z);
    atomicAdd(&acc[dl + 3 * RANGE], v0.w);
    atomicAdd(&acc[dl + 4 * RANGE], v4);
  }
  __syncthreads();
  int node = b * RANGE + t;
  if (node >= n) return;
  float di = dinv[node];
  float A[5];
#pragma unroll
  for (int j = 0; j < 5; ++j) A[j] = acc[t + j * RANGE] + y[(size_t)node * 8 + j];
  float out2 = 0.f;
#pragma unroll
  for (int f = 0; f < 16; ++f) {
    float h = sb1[f];
#pragma unroll
    for (int j = 0; j < 5; ++j) h = fmaf(A[j], sW1[j * 16 + f], h * (j == 0 ? 1.f : 1.f));
    // h = b1[f] + sum_j A[j]*W1[j][f]; apply dinv then relu
    float v = fmaxf(fmaf(di, h - sb1[f], sb1[f]), 0.f);
    out2 = fmaf(v, sW2[f], out2);
  }
  z[node] = di * out2;
}

// ---- pass 6: layer-2 aggregate scalar z, fused bias -> out -----------------
__global__ void __launch_bounds__(256) k_agg2(const int* __restrict__ bins,
                                              const int* __restrict__ binOff,
                                              const float* __restrict__ z,
                                              const float* __restrict__ dinv,
                                              const float* __restrict__ b2,
                                              float* __restrict__ out, int n) {
  __shared__ float acc[RANGE];
  int t = threadIdx.x;
  acc[t] = 0.f;
  __syncthreads();
  int b = blockIdx.x;
  int k0 = binOff[b], k1 = binOff[b + 1];
  for (int k = k0 + t; k < k1; k += 256) {
    unsigned e4 = (unsigned)bins[k];
    atomicAdd(&acc[e4 >> 24], z[e4 & 0xFFFFFF]);
  }
  __syncthreads();
  int node = b * RANGE + t;
  if (node < n) out[node] = fmaf(dinv[node], acc[t] + z[node], b2[0]);
}

extern "C" void kernel_launch(void* const* d_in, const int* in_sizes, int n_in,
                              void* d_out, int out_size, void* d_ws, size_t ws_size,
                              hipStream_t stream) {
  const float* x  = (const float*)d_in[0];
  const float* W1 = (const float*)d_in[1];
  const float* b1 = (const float*)d_in[2];
  const float* W2 = (const float*)d_in[3];
  const float* b2 = (const float*)d_in[4];
  const int*   ei = (const int*)d_in[5];

  int n = in_sizes[0] / 5;
  int e = in_sizes[5] / 2;
  const int* src = ei;
  const int* dst = ei + e;
  int nb = (n + RANGE - 1) / RANGE;  // 391

  char* ws = (char*)d_ws;
  int*   bins     = (int*)ws;   ws += (size_t)e * sizeof(int);
  float* y        = (float*)ws; ws += (size_t)nb * RANGE * 8 * sizeof(float);
  float* dinv     = (float*)ws; ws += (size_t)n * sizeof(float);
  float* z        = (float*)ws; ws += (size_t)n * sizeof(float);
  int*   binTotal = (int*)ws;   ws += (size_t)nb * sizeof(int);
  int*   binOff   = (int*)ws;   ws += (size_t)(nb + 1) * sizeof(int);
  int*   cursor   = (int*)ws;   ws += (size_t)nb * sizeof(int);

  float* out = (float*)d_out;

  int chunks = (e + CHUNK - 1) / CHUNK;

  hipMemsetAsync(binTotal, 0, (size_t)nb * sizeof(int), stream);
  k_count<<<chunks, 256, nb * sizeof(int), stream>>>(dst, binTotal, e, nb);
  k_scan<<<1, 512, 0, stream>>>(binTotal, binOff, cursor, nb, e);
  k_place<<<chunks, 256, 0, stream>>>(src, dst, cursor, bins, e, nb);
  k_deg_y<<<nb, 256, 0, stream>>>(bins, binOff, x, dinv, y, n);
  k_agg1<<<nb, 256, 0, stream>>>(bins, binOff, y, dinv, W1, b1, W2, z, n);
  k_agg2<<<nb, 256, 0, stream>>>(bins, binOff, z, dinv, b2, out, n);
}

// Round 4
// 219.275 us; speedup vs baseline: 4.3130x; 1.0210x over previous
//
#include <hip/hip_runtime.h>

// 2-layer GCN, N=100000 (F0=5, F1=16, F2=1), E=3200000.
// Binned formulation (no global float atomics, no scattered 4B writes):
//   bin b owns nodes [b*256, b*256+256); entry = (dst&255)<<24 | src.
//   y[i]    = dinv[i] * x[i]                  (5 floats, padded to 8; 3.2MB L2-resident)
//   A5[i]   = sum_{s->i} y[s] + y[i]          (LDS accumulate per bin)
//   z[i]    = dinv[i] * (relu(dinv[i]*(A5[i]@W1) + b1) @ W2)
//   out[i]  = dinv[i] * (sum_{s->i} z[s] + z[i]) + b2

constexpr int CHUNK = 4096;   // edges per k_place block
constexpr int RANGE = 256;    // nodes per bin

// ---- pass 1: per-bin edge counts -------------------------------------------
__global__ void k_count(const int* __restrict__ dst, int* __restrict__ binTotal,
                        int e, int nb) {
  extern __shared__ int sh[];
  int* hist = sh;  // nb ints
  for (int b = threadIdx.x; b < nb; b += blockDim.x) hist[b] = 0;
  __syncthreads();
  int stride = gridDim.x * blockDim.x;
  for (int i = blockIdx.x * blockDim.x + threadIdx.x; i < e; i += stride)
    atomicAdd(&hist[dst[i] >> 8], 1);
  __syncthreads();
  for (int b = threadIdx.x; b < nb; b += blockDim.x)
    if (hist[b]) atomicAdd(&binTotal[b], hist[b]);
}

// ---- pass 2: scan bin totals -> binOff, init cursor ------------------------
__global__ void __launch_bounds__(512) k_scan(const int* __restrict__ binTotal,
                                              int* __restrict__ binOff,
                                              int* __restrict__ cursor,
                                              int nb, int e) {
  __shared__ int s[512];
  int t = threadIdx.x;
  int v = (t < nb) ? binTotal[t] : 0;
  s[t] = v;
  __syncthreads();
  for (int d = 1; d < 512; d <<= 1) {
    int u = (t >= d) ? s[t - d] : 0;
    __syncthreads();
    s[t] += u;
    __syncthreads();
  }
  if (t < nb) {
    int excl = s[t] - v;
    binOff[t] = excl;
    cursor[t] = excl;
  }
  if (t == 0) binOff[nb] = e;
}

// ---- pass 3: LDS counting-sort each chunk into bins (coalesced writes) -----
__global__ void __launch_bounds__(256) k_place(const int* __restrict__ src,
                                               const int* __restrict__ dst,
                                               int* __restrict__ cursor,
                                               int* __restrict__ bins,
                                               int e, int nb) {
  __shared__ int entry4[CHUNK];
  __shared__ short bin2[CHUNK];
  __shared__ int hist[512], scan[512], lofs[512], base[512], pcur[512];
  int t = threadIdx.x;
  int e0 = blockIdx.x * CHUNK;
  int cnt = e - e0; if (cnt > CHUNK) cnt = CHUNK;

  for (int b = t; b < 512; b += 256) { hist[b] = 0; }
  __syncthreads();
  for (int i = t; i < cnt; i += 256) atomicAdd(&hist[dst[e0 + i] >> 8], 1);
  __syncthreads();
  // inclusive scan of hist[0..511] with 256 threads (2 elems each)
  scan[t] = hist[t]; scan[t + 256] = hist[t + 256];
  __syncthreads();
  for (int d = 1; d < 512; d <<= 1) {
    int v0 = (t >= d) ? scan[t - d] : 0;
    int v1 = (t + 256 >= d) ? scan[t + 256 - d] : 0;
    __syncthreads();
    scan[t] += v0; scan[t + 256] += v1;
    __syncthreads();
  }
  for (int b = t; b < 512; b += 256) {
    int lo = scan[b] - hist[b];
    lofs[b] = lo;
    pcur[b] = lo;
    if (b < nb && hist[b]) base[b] = atomicAdd(&cursor[b], hist[b]);
  }
  __syncthreads();
  // bin-sort chunk into LDS
  for (int i = t; i < cnt; i += 256) {
    int d = dst[e0 + i];
    int b = d >> 8;
    int slot = atomicAdd(&pcur[b], 1);
    entry4[slot] = ((d & 255) << 24) | src[e0 + i];
    bin2[slot] = (short)b;
  }
  __syncthreads();
  // linear write-out: consecutive slots in a bin-run -> consecutive global pos
  for (int i = t; i < cnt; i += 256) {
    int b = bin2[i];
    bins[base[b] + (i - lofs[b])] = entry4[i];
  }
}

// ---- pass 4: per-bin degree count; write dinv and y = dinv*x (padded 8) ----
__global__ void __launch_bounds__(1024) k_deg_y(const int* __restrict__ bins,
                                                const int* __restrict__ binOff,
                                                const float* __restrict__ x,
                                                float* __restrict__ dinv,
                                                float* __restrict__ y, int n) {
  __shared__ int deg[RANGE];
  int t = threadIdx.x;
  if (t < RANGE) deg[t] = 0;
  __syncthreads();
  int b = blockIdx.x;
  int k0 = binOff[b], k1 = binOff[b + 1];
  int k = k0 + t;
  for (; k + 1024 < k1; k += 2048) {
    unsigned ea = (unsigned)bins[k];
    unsigned eb = (unsigned)bins[k + 1024];
    atomicAdd(&deg[ea >> 24], 1);
    atomicAdd(&deg[eb >> 24], 1);
  }
  if (k < k1) atomicAdd(&deg[((unsigned)bins[k]) >> 24], 1);
  __syncthreads();
  if (t >= RANGE) return;
  int node = b * RANGE + t;
  if (node >= n) return;
  float d = rsqrtf((float)(deg[t] + 1));
  dinv[node] = d;
  float4 a, c;
  a.x = d * x[node * 5 + 0];
  a.y = d * x[node * 5 + 1];
  a.z = d * x[node * 5 + 2];
  a.w = d * x[node * 5 + 3];
  c.x = d * x[node * 5 + 4];
  c.y = c.z = c.w = 0.f;
  ((float4*)y)[(size_t)node * 2 + 0] = a;
  ((float4*)y)[(size_t)node * 2 + 1] = c;
}

// ---- pass 5: layer-1 aggregate in 5-dim, fused @W1 + relu + @W2 -> z -------
__global__ void __launch_bounds__(1024) k_agg1(const int* __restrict__ bins,
                                               const int* __restrict__ binOff,
                                               const float* __restrict__ y,
                                               const float* __restrict__ dinv,
                                               const float* __restrict__ W1,
                                               const float* __restrict__ b1,
                                               const float* __restrict__ W2,
                                               float* __restrict__ z, int n) {
  __shared__ float acc[RANGE * 5];   // acc[node*5 + j] — 5 consecutive banks/edge
  __shared__ float sW1[80], sb1[16], sW2[16];
  int t = threadIdx.x;
  if (t < 80) sW1[t] = W1[t];
  else if (t < 96) sb1[t - 80] = b1[t - 80];
  else if (t < 112) sW2[t - 96] = W2[t - 96];
  for (int j = t; j < RANGE * 5; j += 1024) acc[j] = 0.f;
  __syncthreads();
  int b = blockIdx.x;
  int k0 = binOff[b], k1 = binOff[b + 1];
  int k = k0 + t;
  for (; k + 1024 < k1; k += 2048) {
    unsigned ea = (unsigned)bins[k];
    unsigned eb = (unsigned)bins[k + 1024];
    int da = (ea >> 24) * 5, sa = ea & 0xFFFFFF;
    int db = (eb >> 24) * 5, sb = eb & 0xFFFFFF;
    float4 va = ((const float4*)y)[(size_t)sa * 2 / 5 * 0 + (size_t)(ea & 0xFFFFFF) * 2];
    float va4 = y[(size_t)sa * 8 / 5 * 0 + (size_t)(ea & 0xFFFFFF) * 8 + 4];
    float4 vb = ((const float4*)y)[(size_t)sb * 2];
    float vb4 = y[(size_t)sb * 8 + 4];
    atomicAdd(&acc[da + 0], va.x);
    atomicAdd(&acc[da + 1], va.y);
    atomicAdd(&acc[da + 2], va.z);
    atomicAdd(&acc[da + 3], va.w);
    atomicAdd(&acc[da + 4], va4);
    atomicAdd(&acc[db + 0], vb.x);
    atomicAdd(&acc[db + 1], vb.y);
    atomicAdd(&acc[db + 2], vb.z);
    atomicAdd(&acc[db + 3], vb.w);
    atomicAdd(&acc[db + 4], vb4);
  }
  if (k < k1) {
    unsigned ea = (unsigned)bins[k];
    int da = (ea >> 24) * 5, sa = ea & 0xFFFFFF;
    float4 va = ((const float4*)y)[(size_t)sa * 2];
    float va4 = y[(size_t)sa * 8 + 4];
    atomicAdd(&acc[da + 0], va.x);
    atomicAdd(&acc[da + 1], va.y);
    atomicAdd(&acc[da + 2], va.z);
    atomicAdd(&acc[da + 3], va.w);
    atomicAdd(&acc[da + 4], va4);
  }
  __syncthreads();
  if (t >= RANGE) return;
  int node = b * RANGE + t;
  if (node >= n) return;
  float di = dinv[node];
  float A[5];
#pragma unroll
  for (int j = 0; j < 5; ++j) A[j] = acc[t * 5 + j] + y[(size_t)node * 8 + j];
  float o = 0.f;
#pragma unroll
  for (int f = 0; f < 16; ++f) {
    float h = 0.f;
#pragma unroll
    for (int j = 0; j < 5; ++j) h = fmaf(A[j], sW1[j * 16 + f], h);
    float v = fmaxf(fmaf(di, h, sb1[f]), 0.f);
    o = fmaf(v, sW2[f], o);
  }
  z[node] = di * o;
}

// ---- pass 6: layer-2 aggregate scalar z, fused bias -> out -----------------
__global__ void __launch_bounds__(1024) k_agg2(const int* __restrict__ bins,
                                               const int* __restrict__ binOff,
                                               const float* __restrict__ z,
                                               const float* __restrict__ dinv,
                                               const float* __restrict__ b2,
                                               float* __restrict__ out, int n) {
  __shared__ float acc[RANGE];
  int t = threadIdx.x;
  if (t < RANGE) acc[t] = 0.f;
  __syncthreads();
  int b = blockIdx.x;
  int k0 = binOff[b], k1 = binOff[b + 1];
  int k = k0 + t;
  for (; k + 1024 < k1; k += 2048) {
    unsigned ea = (unsigned)bins[k];
    unsigned eb = (unsigned)bins[k + 1024];
    float za = z[ea & 0xFFFFFF];
    float zb = z[eb & 0xFFFFFF];
    atomicAdd(&acc[ea >> 24], za);
    atomicAdd(&acc[eb >> 24], zb);
  }
  if (k < k1) {
    unsigned ea = (unsigned)bins[k];
    atomicAdd(&acc[ea >> 24], z[ea & 0xFFFFFF]);
  }
  __syncthreads();
  if (t >= RANGE) return;
  int node = b * RANGE + t;
  if (node < n) out[node] = fmaf(dinv[node], acc[t] + z[node], b2[0]);
}

extern "C" void kernel_launch(void* const* d_in, const int* in_sizes, int n_in,
                              void* d_out, int out_size, void* d_ws, size_t ws_size,
                              hipStream_t stream) {
  const float* x  = (const float*)d_in[0];
  const float* W1 = (const float*)d_in[1];
  const float* b1 = (const float*)d_in[2];
  const float* W2 = (const float*)d_in[3];
  const float* b2 = (const float*)d_in[4];
  const int*   ei = (const int*)d_in[5];

  int n = in_sizes[0] / 5;
  int e = in_sizes[5] / 2;
  const int* src = ei;
  const int* dst = ei + e;
  int nb = (n + RANGE - 1) / RANGE;  // 391

  char* ws = (char*)d_ws;
  int*   bins     = (int*)ws;   ws += (size_t)e * sizeof(int);
  float* y        = (float*)ws; ws += (size_t)nb * RANGE * 8 * sizeof(float);
  float* dinv     = (float*)ws; ws += (size_t)n * sizeof(float);
  float* z        = (float*)ws; ws += (size_t)n * sizeof(float);
  int*   binTotal = (int*)ws;   ws += (size_t)nb * sizeof(int);
  int*   binOff   = (int*)ws;   ws += (size_t)(nb + 1) * sizeof(int);
  int*   cursor   = (int*)ws;   ws += (size_t)nb * sizeof(int);

  float* out = (float*)d_out;

  int chunks = (e + CHUNK - 1) / CHUNK;

  hipMemsetAsync(binTotal, 0, (size_t)nb * sizeof(int), stream);
  k_count<<<chunks, 256, nb * sizeof(int), stream>>>(dst, binTotal, e, nb);
  k_scan<<<1, 512, 0, stream>>>(binTotal, binOff, cursor, nb, e);
  k_place<<<chunks, 256, 0, stream>>>(src, dst, cursor, bins, e, nb);
  k_deg_y<<<nb, 1024, 0, stream>>>(bins, binOff, x, dinv, y, n);
  k_agg1<<<nb, 1024, 0, stream>>>(bins, binOff, y, dinv, W1, b1, W2, z, n);
  k_agg2<<<nb, 1024, 0, stream>>>(bins, binOff, z, dinv, b2, out, n);
}

// Round 5
// 109.884 us; speedup vs baseline: 8.6067x; 1.9955x over previous
//
#include <hip/hip_runtime.h>

// 2-layer GCN, N=100000 (F0=5, F1=16, F2=1), E=3200000.
// dst-sorted-bin formulation; aggregation kernels are atomic-free.
//   bin b owns nodes [b*256, b*256+256) at bins[b*CAP ...]; entry (place) = (dst&255)<<24 | src.
//   k_sortbin: counting-sort bin by dl -> bins hold plain src sorted by dst; roff = run offsets.
//   y[i]   = dinv[i]*x[i] (5 floats padded to 8)
//   z[i]   = dinv[i]*(relu(dinv[i]*(sum_run y[s] + y[i])@W1 + b1)@W2)
//   out[i] = dinv[i]*(sum_run z[s] + z[i]) + b2

constexpr int CHUNK = 4096;   // edges per k_place block
constexpr int RANGE = 256;    // nodes per bin
constexpr int CAP   = 12288;  // slots per bin region (max bin ~8.6K)

__global__ void k_init(int* __restrict__ cursor, int nb) {
  int b = blockIdx.x * blockDim.x + threadIdx.x;
  if (b < nb) cursor[b] = b * CAP;
}

// ---- pass 1: LDS counting-sort each chunk into bin regions (coalesced) -----
__global__ void __launch_bounds__(256) k_place(const int* __restrict__ src,
                                               const int* __restrict__ dst,
                                               int* __restrict__ cursor,
                                               int* __restrict__ bins,
                                               int e, int nb) {
  __shared__ int entry4[CHUNK];
  __shared__ short bin2[CHUNK];
  __shared__ int hist[512], scan[512], lofs[512], base[512], pcur[512];
  int t = threadIdx.x;
  int e0 = blockIdx.x * CHUNK;
  int cnt = e - e0; if (cnt > CHUNK) cnt = CHUNK;

  for (int b = t; b < 512; b += 256) hist[b] = 0;
  __syncthreads();
  for (int i = t; i < cnt; i += 256) atomicAdd(&hist[dst[e0 + i] >> 8], 1);
  __syncthreads();
  scan[t] = hist[t]; scan[t + 256] = hist[t + 256];
  __syncthreads();
  for (int d = 1; d < 512; d <<= 1) {
    int v0 = (t >= d) ? scan[t - d] : 0;
    int v1 = (t + 256 >= d) ? scan[t + 256 - d] : 0;
    __syncthreads();
    scan[t] += v0; scan[t + 256] += v1;
    __syncthreads();
  }
  for (int b = t; b < 512; b += 256) {
    int lo = scan[b] - hist[b];
    lofs[b] = lo;
    pcur[b] = lo;
    if (b < nb && hist[b]) base[b] = atomicAdd(&cursor[b], hist[b]);  // absolute
  }
  __syncthreads();
  for (int i = t; i < cnt; i += 256) {
    int d = dst[e0 + i];
    int b = d >> 8;
    int slot = atomicAdd(&pcur[b], 1);
    entry4[slot] = ((d & 255) << 24) | src[e0 + i];
    bin2[slot] = (short)b;
  }
  __syncthreads();
  for (int i = t; i < cnt; i += 256) {
    int b = bin2[i];
    bins[base[b] + (i - lofs[b])] = entry4[i];
  }
}

// ---- pass 2: per-bin counting sort by dl; emit run offsets, deg->dinv, y ----
__global__ void __launch_bounds__(1024) k_sortbin(int* __restrict__ bins,
                                                  const int* __restrict__ cursor,
                                                  const float* __restrict__ x,
                                                  float* __restrict__ dinv,
                                                  float* __restrict__ y,
                                                  int* __restrict__ roff, int n) {
  __shared__ int sorted[CAP];
  __shared__ int hist[RANGE], sc[RANGE], pcur[RANGE];
  int t = threadIdx.x;
  int b = blockIdx.x;
  int bse = b * CAP;
  int len = cursor[b] - bse;
  if (t < RANGE) hist[t] = 0;
  __syncthreads();
  for (int k = t; k < len; k += 1024)
    atomicAdd(&hist[((unsigned)bins[bse + k]) >> 24], 1);
  __syncthreads();
  if (t < RANGE) sc[t] = hist[t];
  __syncthreads();
  for (int d = 1; d < RANGE; d <<= 1) {
    int v = 0;
    if (t < RANGE && t >= d) v = sc[t - d];
    __syncthreads();
    if (t < RANGE) sc[t] += v;
    __syncthreads();
  }
  if (t < RANGE) pcur[t] = sc[t] - hist[t];
  __syncthreads();
  for (int k = t; k < len; k += 1024) {
    unsigned e4 = (unsigned)bins[bse + k];
    int slot = atomicAdd(&pcur[e4 >> 24], 1);
    sorted[slot] = (int)(e4 & 0xFFFFFF);
  }
  __syncthreads();
  for (int k = t; k < len; k += 1024) bins[bse + k] = sorted[k];
  if (t < RANGE) roff[b * (RANGE + 1) + t] = bse + sc[t] - hist[t];
  if (t == 0) roff[b * (RANGE + 1) + RANGE] = bse + len;
  if (t < RANGE) {
    int node = b * RANGE + t;
    if (node < n) {
      float dv = rsqrtf((float)(hist[t] + 1));
      dinv[node] = dv;
      float4 a, c;
      a.x = dv * x[node * 5 + 0];
      a.y = dv * x[node * 5 + 1];
      a.z = dv * x[node * 5 + 2];
      a.w = dv * x[node * 5 + 3];
      c.x = dv * x[node * 5 + 4];
      c.y = c.z = c.w = 0.f;
      ((float4*)y)[(size_t)node * 2 + 0] = a;
      ((float4*)y)[(size_t)node * 2 + 1] = c;
    }
  }
}

// ---- pass 3: layer-1 — atomic-free segmented gather + fused W1/relu/W2 -----
__global__ void __launch_bounds__(1024) k_agg1(const int* __restrict__ bins,
                                               const int* __restrict__ roff,
                                               const float* __restrict__ y,
                                               const float* __restrict__ dinv,
                                               const float* __restrict__ W1,
                                               const float* __restrict__ b1,
                                               const float* __restrict__ W2,
                                               float* __restrict__ z, int n) {
  __shared__ float sW1[80], sb1[16], sW2[16];
  int t = threadIdx.x;
  if (t < 80) sW1[t] = W1[t];
  else if (t < 96) sb1[t - 80] = b1[t - 80];
  else if (t < 112) sW2[t - 96] = W2[t - 96];
  __syncthreads();
  int g = t >> 2, l4 = t & 3;
  int b = blockIdx.x;
  int node = b * RANGE + g;
  if (node >= n) return;
  int r0 = roff[b * (RANGE + 1) + g];
  int r1 = roff[b * (RANGE + 1) + g + 1];
  float a0 = 0.f, a1 = 0.f, a2 = 0.f, a3 = 0.f, a4 = 0.f;
  for (int k = r0 + l4; k < r1; k += 4) {
    int s = bins[k];
    float4 v = ((const float4*)y)[(size_t)s * 2];
    float v4 = y[(size_t)s * 8 + 4];
    a0 += v.x; a1 += v.y; a2 += v.z; a3 += v.w; a4 += v4;
  }
  a0 += __shfl_xor(a0, 1); a0 += __shfl_xor(a0, 2);
  a1 += __shfl_xor(a1, 1); a1 += __shfl_xor(a1, 2);
  a2 += __shfl_xor(a2, 1); a2 += __shfl_xor(a2, 2);
  a3 += __shfl_xor(a3, 1); a3 += __shfl_xor(a3, 2);
  a4 += __shfl_xor(a4, 1); a4 += __shfl_xor(a4, 2);
  float4 ys = ((const float4*)y)[(size_t)node * 2];
  float ys4 = y[(size_t)node * 8 + 4];
  float A0 = a0 + ys.x, A1 = a1 + ys.y, A2 = a2 + ys.z, A3 = a3 + ys.w, A4 = a4 + ys4;
  float di = dinv[node];
  float o = 0.f;
#pragma unroll
  for (int fi = 0; fi < 4; ++fi) {
    int f = l4 * 4 + fi;
    float h = A0 * sW1[0 * 16 + f];
    h = fmaf(A1, sW1[1 * 16 + f], h);
    h = fmaf(A2, sW1[2 * 16 + f], h);
    h = fmaf(A3, sW1[3 * 16 + f], h);
    h = fmaf(A4, sW1[4 * 16 + f], h);
    float v = fmaxf(fmaf(di, h, sb1[f]), 0.f);
    o = fmaf(v, sW2[f], o);
  }
  o += __shfl_xor(o, 1);
  o += __shfl_xor(o, 2);
  if (l4 == 0) z[node] = di * o;
}

// ---- pass 4: layer-2 — atomic-free segmented gather of scalar z ------------
__global__ void __launch_bounds__(1024) k_agg2(const int* __restrict__ bins,
                                               const int* __restrict__ roff,
                                               const float* __restrict__ z,
                                               const float* __restrict__ dinv,
                                               const float* __restrict__ b2,
                                               float* __restrict__ out, int n) {
  int t = threadIdx.x;
  int g = t >> 2, l4 = t & 3;
  int b = blockIdx.x;
  int node = b * RANGE + g;
  if (node >= n) return;
  int r0 = roff[b * (RANGE + 1) + g];
  int r1 = roff[b * (RANGE + 1) + g + 1];
  float a = 0.f;
  for (int k = r0 + l4; k < r1; k += 4) a += z[bins[k]];
  a += __shfl_xor(a, 1);
  a += __shfl_xor(a, 2);
  if (l4 == 0) out[node] = fmaf(dinv[node], a + z[node], b2[0]);
}

extern "C" void kernel_launch(void* const* d_in, const int* in_sizes, int n_in,
                              void* d_out, int out_size, void* d_ws, size_t ws_size,
                              hipStream_t stream) {
  const float* x  = (const float*)d_in[0];
  const float* W1 = (const float*)d_in[1];
  const float* b1 = (const float*)d_in[2];
  const float* W2 = (const float*)d_in[3];
  const float* b2 = (const float*)d_in[4];
  const int*   ei = (const int*)d_in[5];

  int n = in_sizes[0] / 5;
  int e = in_sizes[5] / 2;
  const int* src = ei;
  const int* dst = ei + e;
  int nb = (n + RANGE - 1) / RANGE;  // 391

  char* ws = (char*)d_ws;
  int*   bins   = (int*)ws;   ws += (size_t)nb * CAP * sizeof(int);
  float* y      = (float*)ws; ws += (size_t)nb * RANGE * 8 * sizeof(float);
  float* dinv   = (float*)ws; ws += (size_t)n * sizeof(float);
  float* z      = (float*)ws; ws += (size_t)n * sizeof(float);
  int*   cursor = (int*)ws;   ws += (size_t)nb * sizeof(int);
  int*   roff   = (int*)ws;   ws += (size_t)nb * (RANGE + 1) * sizeof(int);

  float* out = (float*)d_out;

  int chunks = (e + CHUNK - 1) / CHUNK;

  k_init<<<(nb + 255) / 256, 256, 0, stream>>>(cursor, nb);
  k_place<<<chunks, 256, 0, stream>>>(src, dst, cursor, bins, e, nb);
  k_sortbin<<<nb, 1024, 0, stream>>>(bins, cursor, x, dinv, y, roff, n);
  k_agg1<<<nb, 1024, 0, stream>>>(bins, roff, y, dinv, W1, b1, W2, z, n);
  k_agg2<<<nb, 1024, 0, stream>>>(bins, roff, z, dinv, b2, out, n);
}